// Round 1
// baseline (832.666 us; speedup 1.0000x reference)
//
#include <hip/hip_runtime.h>

// GCN decoder: 3x GraphConv (norm='both', project-then-aggregate), dims 256->128->64->1.
// Structure: degrees -> norms -> CSR(by dst) -> [GEMM -> aggregate]x3.

constexpr int D0 = 256, D1 = 128, D2 = 64;

// ---------------- degree histogram ----------------
__global__ void k_degrees(const int* __restrict__ src, const int* __restrict__ dst,
                          int* __restrict__ dout, int* __restrict__ din, int E) {
  int i = blockIdx.x * blockDim.x + threadIdx.x;
  if (i < E) {
    atomicAdd(&dout[src[i]], 1);
    atomicAdd(&din[dst[i]], 1);
  }
}

// ---------------- norm = clip(deg,1)^-0.5 (exact via double) ----------------
__global__ void k_norms(const int* __restrict__ dout, const int* __restrict__ din,
                        float* __restrict__ ns, float* __restrict__ nd, int N) {
  int i = blockIdx.x * blockDim.x + threadIdx.x;
  if (i < N) {
    int a = dout[i]; if (a < 1) a = 1;
    int b = din[i];  if (b < 1) b = 1;
    ns[i] = (float)(1.0 / sqrt((double)a));
    nd[i] = (float)(1.0 / sqrt((double)b));
  }
}

// ---------------- single-block exclusive scan (shuffle-based) ----------------
__global__ void k_scan(const int* __restrict__ cnt, int* __restrict__ offs, int n) {
  __shared__ int wsum[16];
  __shared__ int carry_s;
  const int lane = threadIdx.x & 63;
  const int wid  = threadIdx.x >> 6;
  const int nw   = blockDim.x >> 6;  // 16
  if (threadIdx.x == 0) carry_s = 0;
  __syncthreads();
  for (int base = 0; base < n; base += blockDim.x) {
    int i = base + (int)threadIdx.x;
    int v = (i < n) ? cnt[i] : 0;
    int x = v;
#pragma unroll
    for (int d = 1; d < 64; d <<= 1) {
      int t = __shfl_up(x, d);
      if (lane >= d) x += t;
    }
    if (lane == 63) wsum[wid] = x;
    __syncthreads();
    if (wid == 0 && lane < nw) {
      int s = wsum[lane];
#pragma unroll
      for (int d = 1; d < 16; d <<= 1) {
        int t = __shfl_up(s, d, 16);
        if (lane >= d) s += t;
      }
      wsum[lane] = s;  // inclusive scan of wave sums
    }
    __syncthreads();
    int wave_excl = (wid == 0) ? 0 : wsum[wid - 1];
    int carry = carry_s;
    if (i < n) offs[i] = carry + wave_excl + x - v;
    __syncthreads();
    if (threadIdx.x == 0) carry_s = carry + wsum[nw - 1];
    __syncthreads();
  }
  if (threadIdx.x == 0) offs[n] = carry_s;
}

// ---------------- CSR fill (bucket scatter) ----------------
__global__ void k_fill(const int* __restrict__ src, const int* __restrict__ dst,
                       const float* __restrict__ ew, int* __restrict__ cursor,
                       int* __restrict__ es, float* __restrict__ ews, int E) {
  int i = blockIdx.x * blockDim.x + threadIdx.x;
  if (i < E) {
    int d = dst[i];
    int p = atomicAdd(&cursor[d], 1);
    es[p] = src[i];
    ews[p] = ew[i];
  }
}

// ---------------- tiled fp32 GEMM: C[M,DOUT] = (A * ns[:,None]) @ W ----------------
// BM=64, BK=32, 256 threads, TM=4 x TN micro-tile. TN = DOUT/16.
template <int K, int DOUT, int TN>
__global__ void k_gemm(const float* __restrict__ A, const float* __restrict__ ns,
                       const float* __restrict__ W, float* __restrict__ C, int M) {
  constexpr int BM = 64, BK = 32, TM = 4;
  constexpr int TX = DOUT / TN;  // 16
  constexpr int TY = BM / TM;    // 16
  constexpr int NT = TX * TY;    // 256
  __shared__ float As[BK][BM + 1];
  __shared__ float Ws[BK][DOUT];
  const int block_row = blockIdx.x * BM;
  const int tid = threadIdx.x;
  const int tx = tid % TX, ty = tid / TX;
  float acc[TM][TN] = {};
  for (int k0 = 0; k0 < K; k0 += BK) {
    for (int idx = tid; idx < BM * BK; idx += NT) {
      int r = idx / BK, c = idx % BK;
      int grow = block_row + r;
      float v = 0.f;
      if (grow < M) v = A[(size_t)grow * K + k0 + c] * ns[grow];
      As[c][r] = v;
    }
    for (int idx = tid; idx < BK * DOUT; idx += NT) {
      int r = idx / DOUT, c = idx % DOUT;
      Ws[r][c] = W[(size_t)(k0 + r) * DOUT + c];
    }
    __syncthreads();
#pragma unroll
    for (int kk = 0; kk < BK; ++kk) {
      float a[TM], b[TN];
#pragma unroll
      for (int i = 0; i < TM; ++i) a[i] = As[kk][ty * TM + i];
#pragma unroll
      for (int j = 0; j < TN; ++j) b[j] = Ws[kk][tx * TN + j];
#pragma unroll
      for (int i = 0; i < TM; ++i)
#pragma unroll
        for (int j = 0; j < TN; ++j) acc[i][j] += a[i] * b[j];
    }
    __syncthreads();
  }
  for (int i = 0; i < TM; ++i) {
    int grow = block_row + ty * TM + i;
    if (grow < M) {
#pragma unroll
      for (int j = 0; j < TN; ++j) C[(size_t)grow * DOUT + tx * TN + j] = acc[i][j];
    }
  }
}

// ---------------- aggregation: out[i,:] = relu?(sum_e w*h[src_e,:] * nd[i] + b) ----------------
template <int D, bool RELU>
__global__ void k_agg(const float* __restrict__ h, const int* __restrict__ offs,
                      const int* __restrict__ es, const float* __restrict__ ews,
                      const float* __restrict__ nd, const float* __restrict__ bias,
                      float* __restrict__ out, int M) {
  int node = blockIdx.x;
  int f = threadIdx.x;
  if (node >= M) return;
  int s0 = offs[node], s1 = offs[node + 1];
  float acc = 0.f;
  for (int k = s0; k < s1; ++k) {
    int s = es[k];
    float w = ews[k];
    acc += h[(size_t)s * D + f] * w;
  }
  float r = acc * nd[node] + bias[f];
  if (RELU) r = fmaxf(r, 0.f);
  out[(size_t)node * D + f] = r;
}

// ---------------- layer-3 matvec: h3[i] = ns[i] * dot(z2[i,:], W3[:,0]) ----------------
__global__ void k_matvec64(const float* __restrict__ z2, const float* __restrict__ ns,
                           const float* __restrict__ W3, float* __restrict__ h3, int M) {
  int lane = threadIdx.x & 63;
  int row = (blockIdx.x * blockDim.x + threadIdx.x) >> 6;
  if (row >= M) return;
  float v = z2[(size_t)row * 64 + lane] * W3[lane];
#pragma unroll
  for (int d = 32; d > 0; d >>= 1) v += __shfl_down(v, d);
  if (lane == 0) h3[row] = v * ns[row];
}

// ---------------- layer-3 aggregation (scalar per node) ----------------
__global__ void k_agg1(const float* __restrict__ h3, const int* __restrict__ offs,
                       const int* __restrict__ es, const float* __restrict__ ews,
                       const float* __restrict__ nd, const float* __restrict__ b3,
                       float* __restrict__ out, int M) {
  int i = blockIdx.x * blockDim.x + threadIdx.x;
  if (i >= M) return;
  int s0 = offs[i], s1 = offs[i + 1];
  float acc = 0.f;
  for (int k = s0; k < s1; ++k) acc += h3[es[k]] * ews[k];
  out[i] = acc * nd[i] + b3[0];
}

extern "C" void kernel_launch(void* const* d_in, const int* in_sizes, int n_in,
                              void* d_out, int out_size, void* d_ws, size_t ws_size,
                              hipStream_t stream) {
  const float* b_z = (const float*)d_in[0];
  const int*   src = (const int*)d_in[1];
  const int*   dst = (const int*)d_in[2];
  const float* ew  = (const float*)d_in[3];
  const float* W1  = (const float*)d_in[5];
  const float* b1  = (const float*)d_in[6];
  const float* W2  = (const float*)d_in[7];
  const float* b2  = (const float*)d_in[8];
  const float* W3  = (const float*)d_in[9];
  const float* b3  = (const float*)d_in[10];
  const int N = in_sizes[0] / D0;
  const int E = in_sizes[1];
  float* out = (float*)d_out;

  char* ws = (char*)d_ws;
  size_t off_b = 0;
  auto alloc = [&](size_t bytes) -> void* {
    void* p = ws + off_b;
    off_b += (bytes + 255) & ~(size_t)255;
    return p;
  };
  int*   deg_out = (int*)alloc((size_t)N * 4);
  int*   deg_in  = (int*)alloc((size_t)N * 4);
  int*   offs    = (int*)alloc((size_t)(N + 1) * 4);
  int*   cursor  = (int*)alloc((size_t)N * 4);
  int*   es      = (int*)alloc((size_t)E * 4);
  float* ews     = (float*)alloc((size_t)E * 4);
  float* nsrc    = (float*)alloc((size_t)N * 4);
  float* ndst    = (float*)alloc((size_t)N * 4);
  float* h1      = (float*)alloc((size_t)N * D1 * 4);
  float* z1      = (float*)alloc((size_t)N * D1 * 4);
  float* h3      = (float*)alloc((size_t)N * 4);
  float* h2 = h1;                       // layer-2 GEMM out (h1 dead by then)
  float* z2 = h1 + (size_t)N * D2;      // layer-2 agg out

  hipMemsetAsync(deg_out, 0, (size_t)N * 4, stream);
  hipMemsetAsync(deg_in, 0, (size_t)N * 4, stream);
  k_degrees<<<(E + 255) / 256, 256, 0, stream>>>(src, dst, deg_out, deg_in, E);
  k_norms<<<(N + 255) / 256, 256, 0, stream>>>(deg_out, deg_in, nsrc, ndst, N);
  k_scan<<<1, 1024, 0, stream>>>(deg_in, offs, N);
  hipMemcpyAsync(cursor, offs, (size_t)N * 4, hipMemcpyDeviceToDevice, stream);
  k_fill<<<(E + 255) / 256, 256, 0, stream>>>(src, dst, ew, cursor, es, ews, E);

  // layer 1: 256 -> 128, relu
  k_gemm<D0, D1, 8><<<(N + 63) / 64, 256, 0, stream>>>(b_z, nsrc, W1, h1, N);
  k_agg<D1, true><<<N, D1, 0, stream>>>(h1, offs, es, ews, ndst, b1, z1, N);
  // layer 2: 128 -> 64, relu
  k_gemm<D1, D2, 4><<<(N + 63) / 64, 256, 0, stream>>>(z1, nsrc, W2, h2, N);
  k_agg<D2, true><<<N, D2, 0, stream>>>(h2, offs, es, ews, ndst, b2, z2, N);
  // layer 3: 64 -> 1, no act
  k_matvec64<<<((size_t)N * 64 + 255) / 256, 256, 0, stream>>>(z2, nsrc, W3, h3, N);
  k_agg1<<<(N + 255) / 256, 256, 0, stream>>>(h3, offs, es, ews, ndst, b3, out, N);
}

// Round 2
// 760.468 us; speedup vs baseline: 1.0949x; 1.0949x over previous
//
#include <hip/hip_runtime.h>

// GCN decoder: degrees -> norms -> CSR(by dst) -> [GEMM(MFMA bf16-split) -> aggregate]x3.
// GEMMs use 2-way bf16 split (hi+lo) with 3 MFMA per tile-pair for ~fp32 accuracy.

constexpr int D0 = 256, D1 = 128, D2 = 64;

typedef __attribute__((ext_vector_type(2))) float f32x2;
typedef __attribute__((ext_vector_type(4))) float f32x4;
typedef __attribute__((ext_vector_type(8))) short short8;

__device__ inline unsigned short f2bf(float f) {
  unsigned u = __builtin_bit_cast(unsigned, f);
  u += 0x7fffu + ((u >> 16) & 1u);
  return (unsigned short)(u >> 16);
}
__device__ inline float bf2f(unsigned short h) {
  unsigned u = ((unsigned)h) << 16;
  return __builtin_bit_cast(float, u);
}

// ---------------- degree histogram ----------------
__global__ void k_degrees(const int* __restrict__ src, const int* __restrict__ dst,
                          int* __restrict__ dout, int* __restrict__ din, int E) {
  int i = blockIdx.x * blockDim.x + threadIdx.x;
  if (i < E) {
    atomicAdd(&dout[src[i]], 1);
    atomicAdd(&din[dst[i]], 1);
  }
}

// ---------------- norm = clip(deg,1)^-0.5 ----------------
__global__ void k_norms(const int* __restrict__ dout, const int* __restrict__ din,
                        float* __restrict__ ns, float* __restrict__ nd, int N) {
  int i = blockIdx.x * blockDim.x + threadIdx.x;
  if (i < N) {
    int a = dout[i]; if (a < 1) a = 1;
    int b = din[i];  if (b < 1) b = 1;
    ns[i] = (float)(1.0 / sqrt((double)a));
    nd[i] = (float)(1.0 / sqrt((double)b));
  }
}

// ---------------- single-block exclusive scan ----------------
__global__ void k_scan(const int* __restrict__ cnt, int* __restrict__ offs, int n) {
  __shared__ int wsum[16];
  __shared__ int carry_s;
  const int lane = threadIdx.x & 63;
  const int wid  = threadIdx.x >> 6;
  const int nw   = blockDim.x >> 6;  // 16
  if (threadIdx.x == 0) carry_s = 0;
  __syncthreads();
  for (int base = 0; base < n; base += blockDim.x) {
    int i = base + (int)threadIdx.x;
    int v = (i < n) ? cnt[i] : 0;
    int x = v;
#pragma unroll
    for (int d = 1; d < 64; d <<= 1) {
      int t = __shfl_up(x, d);
      if (lane >= d) x += t;
    }
    if (lane == 63) wsum[wid] = x;
    __syncthreads();
    if (wid == 0 && lane < nw) {
      int s = wsum[lane];
#pragma unroll
      for (int d = 1; d < 16; d <<= 1) {
        int t = __shfl_up(s, d, 16);
        if (lane >= d) s += t;
      }
      wsum[lane] = s;
    }
    __syncthreads();
    int wave_excl = (wid == 0) ? 0 : wsum[wid - 1];
    int carry = carry_s;
    if (i < n) offs[i] = carry + wave_excl + x - v;
    __syncthreads();
    if (threadIdx.x == 0) carry_s = carry + wsum[nw - 1];
    __syncthreads();
  }
  if (threadIdx.x == 0) offs[n] = carry_s;
}

// ---------------- CSR fill ----------------
__global__ void k_fill(const int* __restrict__ src, const int* __restrict__ dst,
                       const float* __restrict__ ew, int* __restrict__ cursor,
                       int* __restrict__ es, float* __restrict__ ews, int E) {
  int i = blockIdx.x * blockDim.x + threadIdx.x;
  if (i < E) {
    int d = dst[i];
    int p = atomicAdd(&cursor[d], 1);
    es[p] = src[i];
    ews[p] = ew[i];
  }
}

// ---------------- W split: W[K][N] fp32 -> Wt_hi/Wt_lo [N][K] bf16 ----------------
__global__ void k_wsplit(const float* __restrict__ W, short* __restrict__ hi,
                         short* __restrict__ lo, int K, int N) {
  int t = blockIdx.x * blockDim.x + threadIdx.x;
  if (t < K * N) {
    int k = t / N, n = t % N;
    float f = W[t];
    unsigned short h = f2bf(f);
    hi[(size_t)n * K + k] = (short)h;
    lo[(size_t)n * K + k] = (short)f2bf(f - bf2f(h));
  }
}

// ---------------- MFMA GEMM: C[M,N] = (A * ns[:,None]) @ W,  W given split as [N][K] bf16 ----------------
// BM=128, BN=N (full). 256 threads = 4 waves arranged WR x WC. 2-way bf16 split, 3 MFMA/pair.
// LDS layout fragment-native: [kchunk(4)][row][8 bf16] -> balanced banks (conflict-free).
template <int K, int N, int WR, int WC>
__launch_bounds__(256, 2)
__global__ void k_gemm_mfma(const float* __restrict__ A, const float* __restrict__ ns,
                            const short* __restrict__ Wth, const short* __restrict__ Wtl,
                            float* __restrict__ C, int M) {
  constexpr int MR = 128 / WR / 16;
  constexpr int NC = N / WC / 16;
  __shared__ short8 Ah[4 * 128], Al[4 * 128];
  __shared__ short8 Bh[4 * N], Bl[4 * N];
  const int t = threadIdx.x;
  const int block_row = blockIdx.x * 128;
  const int lane = t & 63, wid = t >> 6;
  const int wr = wid / WC, wc = wid % WC;
  const int rowbase = wr * (128 / WR), colbase = wc * (N / WC);
  const int c = lane >> 4, lr = lane & 15;
  f32x4 acc[MR][NC] = {};
  const int r = t & 127;
  const int grow = block_row + r;
  float nsv = 0.f;
  if (t < 128 && grow < M) nsv = ns[grow];

  for (int k0 = 0; k0 < K; k0 += 32) {
    if (t < 128) {
      // stage A: one full 128B row-chunk per thread, split to hi/lo bf16
      f32x4 v[8];
      if (grow < M) {
        const f32x4* ap = (const f32x4*)(A + (size_t)grow * K + k0);
#pragma unroll
        for (int i = 0; i < 8; ++i) v[i] = ap[i] * nsv;
      } else {
#pragma unroll
        for (int i = 0; i < 8; ++i) v[i] = f32x4{0.f, 0.f, 0.f, 0.f};
      }
#pragma unroll
      for (int cc = 0; cc < 4; ++cc) {
        short8 hi, lo;
#pragma unroll
        for (int i = 0; i < 8; ++i) {
          float f = v[cc * 2 + (i >> 2)][i & 3];
          unsigned short h = f2bf(f);
          hi[i] = (short)h;
          lo[i] = (short)f2bf(f - bf2f(h));
        }
        Ah[cc * 128 + r] = hi;
        Al[cc * 128 + r] = lo;
      }
    } else {
      // stage B (pre-split bf16, [N][K] layout): direct b128 copies
      const int tt = t - 128;
#pragma unroll
      for (int id = tt; id < N * 4; id += 128) {
        int col = id & (N - 1);
        int cb = id / N;
        Bh[cb * N + col] = *(const short8*)(Wth + (size_t)col * K + k0 + cb * 8);
        Bl[cb * N + col] = *(const short8*)(Wtl + (size_t)col * K + k0 + cb * 8);
      }
    }
    __syncthreads();
    short8 ah[MR], al[MR], bh[NC], bl[NC];
#pragma unroll
    for (int m = 0; m < MR; ++m) {
      int row = rowbase + m * 16 + lr;
      ah[m] = Ah[c * 128 + row];
      al[m] = Al[c * 128 + row];
    }
#pragma unroll
    for (int n = 0; n < NC; ++n) {
      int col = colbase + n * 16 + lr;
      bh[n] = Bh[c * N + col];
      bl[n] = Bl[c * N + col];
    }
#pragma unroll
    for (int m = 0; m < MR; ++m)
#pragma unroll
      for (int n = 0; n < NC; ++n) {
        acc[m][n] = __builtin_amdgcn_mfma_f32_16x16x32_bf16(ah[m], bh[n], acc[m][n], 0, 0, 0);
        acc[m][n] = __builtin_amdgcn_mfma_f32_16x16x32_bf16(ah[m], bl[n], acc[m][n], 0, 0, 0);
        acc[m][n] = __builtin_amdgcn_mfma_f32_16x16x32_bf16(al[m], bh[n], acc[m][n], 0, 0, 0);
      }
    __syncthreads();
  }
  // C store: row = (lane>>4)*4 + j, col = lane&15 within each 16x16 fragment (m89-verified)
#pragma unroll
  for (int m = 0; m < MR; ++m) {
#pragma unroll
    for (int j = 0; j < 4; ++j) {
      int row = block_row + rowbase + m * 16 + (lane >> 4) * 4 + j;
      if (row < M) {
#pragma unroll
        for (int n = 0; n < NC; ++n)
          C[(size_t)row * N + colbase + n * 16 + lr] = acc[m][n][j];
      }
    }
  }
}

// ---------------- aggregation D=128: wave per node, float2 per lane ----------------
__global__ void k_agg128(const float* __restrict__ h, const int* __restrict__ offs,
                         const int* __restrict__ es, const float* __restrict__ ews,
                         const float* __restrict__ nd, const float* __restrict__ bias,
                         float* __restrict__ out, int M) {
  int w = (blockIdx.x * blockDim.x + threadIdx.x) >> 6;
  int lane = threadIdx.x & 63;
  if (w >= M) return;
  int s0 = offs[w], s1 = offs[w + 1];
  const f32x2* hp = (const f32x2*)h;
  float a0 = 0.f, a1 = 0.f;
  for (int k = s0; k < s1; ++k) {
    int s = es[k];
    float wt = ews[k];
    f32x2 v = hp[(size_t)s * 64 + lane];
    a0 += v[0] * wt;
    a1 += v[1] * wt;
  }
  float ndv = nd[w];
  f32x2 b = ((const f32x2*)bias)[lane];
  f32x2 rr;
  rr[0] = fmaxf(a0 * ndv + b[0], 0.f);
  rr[1] = fmaxf(a1 * ndv + b[1], 0.f);
  ((f32x2*)out)[(size_t)w * 64 + lane] = rr;
}

// ---------------- aggregation D=64 fused with 64->1 matvec ----------------
// z2[w,l] = relu(segsum*nd + b2);  h3[w] = ns[w] * sum_l z2[w,l]*W3[l]
__global__ void k_agg64mv(const float* __restrict__ h, const int* __restrict__ offs,
                          const int* __restrict__ es, const float* __restrict__ ews,
                          const float* __restrict__ nd, const float* __restrict__ b2,
                          const float* __restrict__ W3, const float* __restrict__ ns,
                          float* __restrict__ h3, int M) {
  int w = (blockIdx.x * blockDim.x + threadIdx.x) >> 6;
  int lane = threadIdx.x & 63;
  if (w >= M) return;
  int s0 = offs[w], s1 = offs[w + 1];
  float acc = 0.f;
  for (int k = s0; k < s1; ++k) {
    acc += h[(size_t)es[k] * 64 + lane] * ews[k];
  }
  float r = fmaxf(acc * nd[w] + b2[lane], 0.f);
  float p = r * W3[lane];
#pragma unroll
  for (int d = 32; d; d >>= 1) p += __shfl_xor(p, d);
  if (lane == 0) h3[w] = p * ns[w];
}

// ---------------- final scalar aggregation ----------------
__global__ void k_aggfin(const float* __restrict__ h3, const int* __restrict__ offs,
                         const int* __restrict__ es, const float* __restrict__ ews,
                         const float* __restrict__ nd, const float* __restrict__ b3,
                         float* __restrict__ out, int M) {
  int i = blockIdx.x * blockDim.x + threadIdx.x;
  if (i >= M) return;
  int s0 = offs[i], s1 = offs[i + 1];
  float acc = 0.f;
  for (int k = s0; k < s1; ++k) acc += h3[es[k]] * ews[k];
  out[i] = acc * nd[i] + b3[0];
}

extern "C" void kernel_launch(void* const* d_in, const int* in_sizes, int n_in,
                              void* d_out, int out_size, void* d_ws, size_t ws_size,
                              hipStream_t stream) {
  const float* b_z = (const float*)d_in[0];
  const int*   src = (const int*)d_in[1];
  const int*   dst = (const int*)d_in[2];
  const float* ew  = (const float*)d_in[3];
  const float* W1  = (const float*)d_in[5];
  const float* b1  = (const float*)d_in[6];
  const float* W2  = (const float*)d_in[7];
  const float* b2  = (const float*)d_in[8];
  const float* W3  = (const float*)d_in[9];
  const float* b3  = (const float*)d_in[10];
  const int N = in_sizes[0] / D0;
  const int E = in_sizes[1];
  float* out = (float*)d_out;

  char* ws = (char*)d_ws;
  size_t off_b = 0;
  auto alloc = [&](size_t bytes) -> void* {
    void* p = ws + off_b;
    off_b += (bytes + 255) & ~(size_t)255;
    return p;
  };
  int*   deg_out = (int*)alloc((size_t)N * 4);
  int*   deg_in  = (int*)alloc((size_t)N * 4);
  int*   offs    = (int*)alloc((size_t)(N + 1) * 4);
  int*   cursor  = (int*)alloc((size_t)N * 4);
  int*   es      = (int*)alloc((size_t)E * 4);
  float* ews     = (float*)alloc((size_t)E * 4);
  float* nsrc    = (float*)alloc((size_t)N * 4);
  float* ndst    = (float*)alloc((size_t)N * 4);
  float* h1      = (float*)alloc((size_t)N * D1 * 4);
  float* z1      = (float*)alloc((size_t)N * D1 * 4);
  float* h3      = (float*)alloc((size_t)N * 4);
  short* wt1h    = (short*)alloc((size_t)D0 * D1 * 2);
  short* wt1l    = (short*)alloc((size_t)D0 * D1 * 2);
  short* wt2h    = (short*)alloc((size_t)D1 * D2 * 2);
  short* wt2l    = (short*)alloc((size_t)D1 * D2 * 2);
  float* h2 = h1;  // layer-2 GEMM output reuses h1 (dead after agg1)

  hipMemsetAsync(deg_out, 0, (size_t)N * 4, stream);
  hipMemsetAsync(deg_in, 0, (size_t)N * 4, stream);
  k_degrees<<<(E + 255) / 256, 256, 0, stream>>>(src, dst, deg_out, deg_in, E);
  k_norms<<<(N + 255) / 256, 256, 0, stream>>>(deg_out, deg_in, nsrc, ndst, N);
  k_scan<<<1, 1024, 0, stream>>>(deg_in, offs, N);
  hipMemcpyAsync(cursor, offs, (size_t)N * 4, hipMemcpyDeviceToDevice, stream);
  k_fill<<<(E + 255) / 256, 256, 0, stream>>>(src, dst, ew, cursor, es, ews, E);
  k_wsplit<<<(D0 * D1 + 255) / 256, 256, 0, stream>>>(W1, wt1h, wt1l, D0, D1);
  k_wsplit<<<(D1 * D2 + 255) / 256, 256, 0, stream>>>(W2, wt2h, wt2l, D1, D2);

  const int gemm_grid = (N + 127) / 128;
  // layer 1: 256 -> 128
  k_gemm_mfma<D0, D1, 2, 2><<<gemm_grid, 256, 0, stream>>>(b_z, nsrc, wt1h, wt1l, h1, N);
  k_agg128<<<(N + 3) / 4, 256, 0, stream>>>(h1, offs, es, ews, ndst, b1, z1, N);
  // layer 2: 128 -> 64
  k_gemm_mfma<D1, D2, 4, 1><<<gemm_grid, 256, 0, stream>>>(z1, nsrc, wt2h, wt2l, h2, N);
  // layer-2 agg fused with layer-3 projection (64->1 matvec)
  k_agg64mv<<<(N + 3) / 4, 256, 0, stream>>>(h2, offs, es, ews, ndst, b2, W3, nsrc, h3, N);
  // final scalar aggregation
  k_aggfin<<<(N + 255) / 256, 256, 0, stream>>>(h3, offs, es, ews, ndst, b3, out, N);
}

// Round 3
// 515.297 us; speedup vs baseline: 1.6159x; 1.4758x over previous
//
#include <hip/hip_runtime.h>

// GCN decoder: degrees -> norms -> CSR(by dst, hierarchical scan) ->
// [GEMM(MFMA bf16-split) -> aggregate(MLP-unrolled gather)]x3.

constexpr int D0 = 256, D1 = 128, D2 = 64;

typedef __attribute__((ext_vector_type(2))) float f32x2;
typedef __attribute__((ext_vector_type(4))) float f32x4;
typedef __attribute__((ext_vector_type(8))) short short8;

__device__ inline unsigned short f2bf(float f) {
  unsigned u = __builtin_bit_cast(unsigned, f);
  u += 0x7fffu + ((u >> 16) & 1u);
  return (unsigned short)(u >> 16);
}
__device__ inline float bf2f(unsigned short h) {
  unsigned u = ((unsigned)h) << 16;
  return __builtin_bit_cast(float, u);
}
__device__ inline int rdlane_i(int v, int l) { return __builtin_amdgcn_readlane(v, l); }
__device__ inline float rdlane_f(float v, int l) {
  return __builtin_bit_cast(float, __builtin_amdgcn_readlane(__builtin_bit_cast(int, v), l));
}

// ---------------- degree histogram ----------------
__global__ void k_degrees(const int* __restrict__ src, const int* __restrict__ dst,
                          int* __restrict__ dout, int* __restrict__ din, int E) {
  int i = blockIdx.x * blockDim.x + threadIdx.x;
  if (i < E) {
    atomicAdd(&dout[src[i]], 1);
    atomicAdd(&din[dst[i]], 1);
  }
}

// ---------------- norm = clip(deg,1)^-0.5 ----------------
__global__ void k_norms(const int* __restrict__ dout, const int* __restrict__ din,
                        float* __restrict__ ns, float* __restrict__ nd, int N) {
  int i = blockIdx.x * blockDim.x + threadIdx.x;
  if (i < N) {
    int a = dout[i]; if (a < 1) a = 1;
    int b = din[i];  if (b < 1) b = 1;
    ns[i] = (float)(1.0 / sqrt((double)a));
    nd[i] = (float)(1.0 / sqrt((double)b));
  }
}

// ---------------- hierarchical scan: block sums ----------------
__global__ void k_bsum(const int* __restrict__ cnt, int* __restrict__ bsum, int n) {
  __shared__ int ws[4];
  int i = blockIdx.x * 256 + threadIdx.x;
  int v = (i < n) ? cnt[i] : 0;
#pragma unroll
  for (int d = 32; d; d >>= 1) v += __shfl_down(v, d);
  int lane = threadIdx.x & 63, wid = threadIdx.x >> 6;
  if (lane == 0) ws[wid] = v;
  __syncthreads();
  if (threadIdx.x == 0) bsum[blockIdx.x] = ws[0] + ws[1] + ws[2] + ws[3];
}

// ---------------- single-block exclusive scan of partials (nb <= 1024) ----------------
__global__ void k_bscan(int* __restrict__ bsum, int nb, int* __restrict__ total_out) {
  __shared__ int wsum[16];
  int tid = threadIdx.x, lane = tid & 63, wid = tid >> 6;
  int v = (tid < nb) ? bsum[tid] : 0;
  int x = v;
#pragma unroll
  for (int d = 1; d < 64; d <<= 1) { int t = __shfl_up(x, d); if (lane >= d) x += t; }
  if (lane == 63) wsum[wid] = x;
  __syncthreads();
  if (wid == 0 && lane < 16) {
    int s = wsum[lane];
#pragma unroll
    for (int d = 1; d < 16; d <<= 1) { int t = __shfl_up(s, d, 16); if (lane >= d) s += t; }
    wsum[lane] = s;
  }
  __syncthreads();
  int excl = x - v + (wid ? wsum[wid - 1] : 0);
  if (tid < nb) bsum[tid] = excl;
  if (tid == 0) *total_out = wsum[15];
}

// ---------------- per-block rescan + add carry ----------------
__global__ void k_bscan2(const int* __restrict__ cnt, const int* __restrict__ bex,
                         int* __restrict__ offs, int n) {
  __shared__ int wsum[4];
  int i = blockIdx.x * 256 + threadIdx.x;
  int lane = threadIdx.x & 63, wid = threadIdx.x >> 6;
  int v = (i < n) ? cnt[i] : 0;
  int x = v;
#pragma unroll
  for (int d = 1; d < 64; d <<= 1) { int t = __shfl_up(x, d); if (lane >= d) x += t; }
  if (lane == 63) wsum[wid] = x;
  __syncthreads();
  int wexcl = 0;
  for (int q = 0; q < wid; ++q) wexcl += wsum[q];
  if (i < n) offs[i] = bex[blockIdx.x] + wexcl + x - v;
}

// ---------------- CSR fill ----------------
__global__ void k_fill(const int* __restrict__ src, const int* __restrict__ dst,
                       const float* __restrict__ ew, int* __restrict__ cursor,
                       int* __restrict__ es, float* __restrict__ ews, int E) {
  int i = blockIdx.x * blockDim.x + threadIdx.x;
  if (i < E) {
    int d = dst[i];
    int p = atomicAdd(&cursor[d], 1);
    es[p] = src[i];
    ews[p] = ew[i];
  }
}

// ---------------- W split: W[K][N] fp32 -> Wt_hi/Wt_lo [N][K] bf16 ----------------
__global__ void k_wsplit(const float* __restrict__ W, short* __restrict__ hi,
                         short* __restrict__ lo, int K, int N) {
  int t = blockIdx.x * blockDim.x + threadIdx.x;
  if (t < K * N) {
    int k = t / N, n = t % N;
    float f = W[t];
    unsigned short h = f2bf(f);
    hi[(size_t)n * K + k] = (short)h;
    lo[(size_t)n * K + k] = (short)f2bf(f - bf2f(h));
  }
}

// ---------------- MFMA GEMM: C[M,N] = (A * ns[:,None]) @ W ----------------
template <int K, int N, int WR, int WC>
__launch_bounds__(256, 2)
__global__ void k_gemm_mfma(const float* __restrict__ A, const float* __restrict__ ns,
                            const short* __restrict__ Wth, const short* __restrict__ Wtl,
                            float* __restrict__ C, int M) {
  constexpr int MR = 128 / WR / 16;
  constexpr int NC = N / WC / 16;
  __shared__ short8 Ah[4 * 128], Al[4 * 128];
  __shared__ short8 Bh[4 * N], Bl[4 * N];
  const int t = threadIdx.x;
  const int block_row = blockIdx.x * 128;
  const int lane = t & 63, wid = t >> 6;
  const int wr = wid / WC, wc = wid % WC;
  const int rowbase = wr * (128 / WR), colbase = wc * (N / WC);
  const int c = lane >> 4, lr = lane & 15;
  f32x4 acc[MR][NC] = {};
  const int r = t & 127;
  const int grow = block_row + r;
  float nsv = 0.f;
  if (t < 128 && grow < M) nsv = ns[grow];

  for (int k0 = 0; k0 < K; k0 += 32) {
    if (t < 128) {
      f32x4 v[8];
      if (grow < M) {
        const f32x4* ap = (const f32x4*)(A + (size_t)grow * K + k0);
#pragma unroll
        for (int i = 0; i < 8; ++i) v[i] = ap[i] * nsv;
      } else {
#pragma unroll
        for (int i = 0; i < 8; ++i) v[i] = f32x4{0.f, 0.f, 0.f, 0.f};
      }
#pragma unroll
      for (int cc = 0; cc < 4; ++cc) {
        short8 hi, lo;
#pragma unroll
        for (int i = 0; i < 8; ++i) {
          float f = v[cc * 2 + (i >> 2)][i & 3];
          unsigned short h = f2bf(f);
          hi[i] = (short)h;
          lo[i] = (short)f2bf(f - bf2f(h));
        }
        Ah[cc * 128 + r] = hi;
        Al[cc * 128 + r] = lo;
      }
    } else {
      const int tt = t - 128;
#pragma unroll
      for (int id = tt; id < N * 4; id += 128) {
        int col = id & (N - 1);
        int cb = id / N;
        Bh[cb * N + col] = *(const short8*)(Wth + (size_t)col * K + k0 + cb * 8);
        Bl[cb * N + col] = *(const short8*)(Wtl + (size_t)col * K + k0 + cb * 8);
      }
    }
    __syncthreads();
    short8 ah[MR], al[MR], bh[NC], bl[NC];
#pragma unroll
    for (int m = 0; m < MR; ++m) {
      int row = rowbase + m * 16 + lr;
      ah[m] = Ah[c * 128 + row];
      al[m] = Al[c * 128 + row];
    }
#pragma unroll
    for (int n = 0; n < NC; ++n) {
      int col = colbase + n * 16 + lr;
      bh[n] = Bh[c * N + col];
      bl[n] = Bl[c * N + col];
    }
#pragma unroll
    for (int m = 0; m < MR; ++m)
#pragma unroll
      for (int n = 0; n < NC; ++n) {
        acc[m][n] = __builtin_amdgcn_mfma_f32_16x16x32_bf16(ah[m], bh[n], acc[m][n], 0, 0, 0);
        acc[m][n] = __builtin_amdgcn_mfma_f32_16x16x32_bf16(ah[m], bl[n], acc[m][n], 0, 0, 0);
        acc[m][n] = __builtin_amdgcn_mfma_f32_16x16x32_bf16(al[m], bh[n], acc[m][n], 0, 0, 0);
      }
    __syncthreads();
  }
#pragma unroll
  for (int m = 0; m < MR; ++m) {
#pragma unroll
    for (int j = 0; j < 4; ++j) {
      int row = block_row + rowbase + m * 16 + (lane >> 4) * 4 + j;
      if (row < M) {
#pragma unroll
        for (int n = 0; n < NC; ++n)
          C[(size_t)row * N + colbase + n * 16 + lr] = acc[m][n][j];
      }
    }
  }
}

// ---------------- aggregation D=128: wave/node, lane-coop edge load, unroll-8 gathers ----------------
__global__ void k_agg128(const float* __restrict__ h, const int* __restrict__ offs,
                         const int* __restrict__ es, const float* __restrict__ ews,
                         const float* __restrict__ nd, const float* __restrict__ bias,
                         float* __restrict__ out, int M) {
  int w = blockIdx.x * (blockDim.x >> 6) + (threadIdx.x >> 6);
  int lane = threadIdx.x & 63;
  if (w >= M) return;
  int s0 = offs[w], s1 = offs[w + 1];
  const f32x2* hp = (const f32x2*)h;
  float a0 = 0.f, a1 = 0.f;
  for (int base = s0; base < s1; base += 64) {
    int kk = base + lane;
    int sidx = 0;
    float wt = 0.f;
    if (kk < s1) { sidx = es[kk]; wt = ews[kk]; }
    int cnt = min(64, s1 - base);
    for (int jj = 0; jj < cnt; jj += 8) {
      f32x2 v[8];
      float wu[8];
#pragma unroll
      for (int u = 0; u < 8; ++u) {
        int s = rdlane_i(sidx, jj + u);
        wu[u] = rdlane_f(wt, jj + u);
        v[u] = hp[(size_t)(unsigned)s * 64 + lane];
      }
#pragma unroll
      for (int u = 0; u < 8; ++u) {
        a0 += v[u][0] * wu[u];
        a1 += v[u][1] * wu[u];
      }
    }
  }
  float ndv = nd[w];
  f32x2 b = ((const f32x2*)bias)[lane];
  f32x2 rr;
  rr[0] = fmaxf(a0 * ndv + b[0], 0.f);
  rr[1] = fmaxf(a1 * ndv + b[1], 0.f);
  ((f32x2*)out)[(size_t)w * 64 + lane] = rr;
}

// ---------------- aggregation D=64 fused with 64->1 matvec ----------------
__global__ void k_agg64mv(const float* __restrict__ h, const int* __restrict__ offs,
                          const int* __restrict__ es, const float* __restrict__ ews,
                          const float* __restrict__ nd, const float* __restrict__ b2,
                          const float* __restrict__ W3, const float* __restrict__ ns,
                          float* __restrict__ h3, int M) {
  int w = blockIdx.x * (blockDim.x >> 6) + (threadIdx.x >> 6);
  int lane = threadIdx.x & 63;
  if (w >= M) return;
  int s0 = offs[w], s1 = offs[w + 1];
  float acc = 0.f;
  for (int base = s0; base < s1; base += 64) {
    int kk = base + lane;
    int sidx = 0;
    float wt = 0.f;
    if (kk < s1) { sidx = es[kk]; wt = ews[kk]; }
    int cnt = min(64, s1 - base);
    for (int jj = 0; jj < cnt; jj += 8) {
      float v[8], wu[8];
#pragma unroll
      for (int u = 0; u < 8; ++u) {
        int s = rdlane_i(sidx, jj + u);
        wu[u] = rdlane_f(wt, jj + u);
        v[u] = h[(size_t)(unsigned)s * 64 + lane];
      }
#pragma unroll
      for (int u = 0; u < 8; ++u) acc += v[u] * wu[u];
    }
  }
  float r = fmaxf(acc * nd[w] + b2[lane], 0.f);
  float p = r * W3[lane];
#pragma unroll
  for (int d = 32; d; d >>= 1) p += __shfl_xor(p, d);
  if (lane == 0) h3[w] = p * ns[w];
}

// ---------------- final scalar aggregation ----------------
__global__ void k_aggfin(const float* __restrict__ h3, const int* __restrict__ offs,
                         const int* __restrict__ es, const float* __restrict__ ews,
                         const float* __restrict__ nd, const float* __restrict__ b3,
                         float* __restrict__ out, int M) {
  int i = blockIdx.x * blockDim.x + threadIdx.x;
  if (i >= M) return;
  int s0 = offs[i], s1 = offs[i + 1];
  float acc = 0.f;
  int k = s0;
  for (; k + 4 <= s1; k += 4) {
    float x0 = h3[es[k]] * ews[k];
    float x1 = h3[es[k + 1]] * ews[k + 1];
    float x2 = h3[es[k + 2]] * ews[k + 2];
    float x3 = h3[es[k + 3]] * ews[k + 3];
    acc += x0 + x1 + x2 + x3;
  }
  for (; k < s1; ++k) acc += h3[es[k]] * ews[k];
  out[i] = acc * nd[i] + b3[0];
}

extern "C" void kernel_launch(void* const* d_in, const int* in_sizes, int n_in,
                              void* d_out, int out_size, void* d_ws, size_t ws_size,
                              hipStream_t stream) {
  const float* b_z = (const float*)d_in[0];
  const int*   src = (const int*)d_in[1];
  const int*   dst = (const int*)d_in[2];
  const float* ew  = (const float*)d_in[3];
  const float* W1  = (const float*)d_in[5];
  const float* b1  = (const float*)d_in[6];
  const float* W2  = (const float*)d_in[7];
  const float* b2  = (const float*)d_in[8];
  const float* W3  = (const float*)d_in[9];
  const float* b3  = (const float*)d_in[10];
  const int N = in_sizes[0] / D0;
  const int E = in_sizes[1];
  float* out = (float*)d_out;

  char* ws = (char*)d_ws;
  size_t off_b = 0;
  auto alloc = [&](size_t bytes) -> void* {
    void* p = ws + off_b;
    off_b += (bytes + 255) & ~(size_t)255;
    return p;
  };
  int*   deg_out = (int*)alloc((size_t)N * 4);
  int*   deg_in  = (int*)alloc((size_t)N * 4);
  int*   offs    = (int*)alloc((size_t)(N + 1) * 4);
  int*   cursor  = (int*)alloc((size_t)N * 4);
  int*   bsum    = (int*)alloc((size_t)1024 * 4);
  int*   es      = (int*)alloc((size_t)E * 4);
  float* ews     = (float*)alloc((size_t)E * 4);
  float* nsrc    = (float*)alloc((size_t)N * 4);
  float* ndst    = (float*)alloc((size_t)N * 4);
  float* h1      = (float*)alloc((size_t)N * D1 * 4);
  float* z1      = (float*)alloc((size_t)N * D1 * 4);
  float* h3      = (float*)alloc((size_t)N * 4);
  short* wt1h    = (short*)alloc((size_t)D0 * D1 * 2);
  short* wt1l    = (short*)alloc((size_t)D0 * D1 * 2);
  short* wt2h    = (short*)alloc((size_t)D1 * D2 * 2);
  short* wt2l    = (short*)alloc((size_t)D1 * D2 * 2);
  float* h2 = h1;  // layer-2 GEMM output reuses h1 (dead after agg1)

  const int nb = (N + 255) / 256;  // 391

  hipMemsetAsync(deg_out, 0, (size_t)N * 4, stream);
  hipMemsetAsync(deg_in, 0, (size_t)N * 4, stream);
  k_degrees<<<(E + 255) / 256, 256, 0, stream>>>(src, dst, deg_out, deg_in, E);
  k_norms<<<(N + 255) / 256, 256, 0, stream>>>(deg_out, deg_in, nsrc, ndst, N);
  k_bsum<<<nb, 256, 0, stream>>>(deg_in, bsum, N);
  k_bscan<<<1, 1024, 0, stream>>>(bsum, nb, &offs[N]);
  k_bscan2<<<nb, 256, 0, stream>>>(deg_in, bsum, offs, N);
  hipMemcpyAsync(cursor, offs, (size_t)N * 4, hipMemcpyDeviceToDevice, stream);
  k_fill<<<(E + 255) / 256, 256, 0, stream>>>(src, dst, ew, cursor, es, ews, E);
  k_wsplit<<<(D0 * D1 + 255) / 256, 256, 0, stream>>>(W1, wt1h, wt1l, D0, D1);
  k_wsplit<<<(D1 * D2 + 255) / 256, 256, 0, stream>>>(W2, wt2h, wt2l, D1, D2);

  const int gemm_grid = (N + 127) / 128;
  // layer 1: 256 -> 128
  k_gemm_mfma<D0, D1, 2, 2><<<gemm_grid, 256, 0, stream>>>(b_z, nsrc, wt1h, wt1l, h1, N);
  k_agg128<<<(N + 3) / 4, 256, 0, stream>>>(h1, offs, es, ews, ndst, b1, z1, N);
  // layer 2: 128 -> 64
  k_gemm_mfma<D1, D2, 4, 1><<<gemm_grid, 256, 0, stream>>>(z1, nsrc, wt2h, wt2l, h2, N);
  // layer-2 agg fused with layer-3 projection (64->1 matvec)
  k_agg64mv<<<(N + 3) / 4, 256, 0, stream>>>(h2, offs, es, ews, ndst, b2, W3, nsrc, h3, N);
  // final scalar aggregation
  k_aggfin<<<(N + 255) / 256, 256, 0, stream>>>(h3, offs, es, ews, ndst, b3, out, N);
}

// Round 4
// 454.873 us; speedup vs baseline: 1.8305x; 1.1328x over previous
//
#include <hip/hip_runtime.h>

// GCN decoder: degrees(+rank) -> norms -> scan -> binned CSR fill (no atomic) ->
// [GEMM(MFMA bf16-split) -> aggregate(readlane-unrolled gather)]x3.

constexpr int D0 = 256, D1 = 128, D2 = 64;

typedef __attribute__((ext_vector_type(2))) float f32x2;
typedef __attribute__((ext_vector_type(4))) float f32x4;
typedef __attribute__((ext_vector_type(8))) short short8;

__device__ inline unsigned short f2bf(float f) {
  unsigned u = __builtin_bit_cast(unsigned, f);
  u += 0x7fffu + ((u >> 16) & 1u);
  return (unsigned short)(u >> 16);
}
__device__ inline float bf2f(unsigned short h) {
  unsigned u = ((unsigned)h) << 16;
  return __builtin_bit_cast(float, u);
}
__device__ inline int rdlane_i(int v, int l) { return __builtin_amdgcn_readlane(v, l); }
__device__ inline float rdlane_f(float v, int l) {
  return __builtin_bit_cast(float, __builtin_amdgcn_readlane(__builtin_bit_cast(int, v), l));
}

// ---------------- degree histogram + in-bucket rank ----------------
__global__ void k_degrees(const int* __restrict__ src, const int* __restrict__ dst,
                          int* __restrict__ dout, int* __restrict__ din,
                          int* __restrict__ rank, int E) {
  int i = blockIdx.x * blockDim.x + threadIdx.x;
  if (i < E) {
    atomicAdd(&dout[src[i]], 1);
    rank[i] = atomicAdd(&din[dst[i]], 1);
  }
}

// ---------------- norm = clip(deg,1)^-0.5 ----------------
__global__ void k_norms(const int* __restrict__ dout, const int* __restrict__ din,
                        float* __restrict__ ns, float* __restrict__ nd, int N) {
  int i = blockIdx.x * blockDim.x + threadIdx.x;
  if (i < N) {
    int a = dout[i]; if (a < 1) a = 1;
    int b = din[i];  if (b < 1) b = 1;
    ns[i] = (float)(1.0 / sqrt((double)a));
    nd[i] = (float)(1.0 / sqrt((double)b));
  }
}

// ---------------- hierarchical scan: block sums ----------------
__global__ void k_bsum(const int* __restrict__ cnt, int* __restrict__ bsum, int n) {
  __shared__ int ws[4];
  int i = blockIdx.x * 256 + threadIdx.x;
  int v = (i < n) ? cnt[i] : 0;
#pragma unroll
  for (int d = 32; d; d >>= 1) v += __shfl_down(v, d);
  int lane = threadIdx.x & 63, wid = threadIdx.x >> 6;
  if (lane == 0) ws[wid] = v;
  __syncthreads();
  if (threadIdx.x == 0) bsum[blockIdx.x] = ws[0] + ws[1] + ws[2] + ws[3];
}

// ---------------- single-block exclusive scan of partials (nb <= 1024) ----------------
__global__ void k_bscan(int* __restrict__ bsum, int nb, int* __restrict__ total_out) {
  __shared__ int wsum[16];
  int tid = threadIdx.x, lane = tid & 63, wid = tid >> 6;
  int v = (tid < nb) ? bsum[tid] : 0;
  int x = v;
#pragma unroll
  for (int d = 1; d < 64; d <<= 1) { int t = __shfl_up(x, d); if (lane >= d) x += t; }
  if (lane == 63) wsum[wid] = x;
  __syncthreads();
  if (wid == 0 && lane < 16) {
    int s = wsum[lane];
#pragma unroll
    for (int d = 1; d < 16; d <<= 1) { int t = __shfl_up(s, d, 16); if (lane >= d) s += t; }
    wsum[lane] = s;
  }
  __syncthreads();
  int excl = x - v + (wid ? wsum[wid - 1] : 0);
  if (tid < nb) bsum[tid] = excl;
  if (tid == 0) *total_out = wsum[15];
}

// ---------------- per-block rescan + add carry ----------------
__global__ void k_bscan2(const int* __restrict__ cnt, const int* __restrict__ bex,
                         int* __restrict__ offs, int n) {
  __shared__ int wsum[4];
  int i = blockIdx.x * 256 + threadIdx.x;
  int lane = threadIdx.x & 63, wid = threadIdx.x >> 6;
  int v = (i < n) ? cnt[i] : 0;
  int x = v;
#pragma unroll
  for (int d = 1; d < 64; d <<= 1) { int t = __shfl_up(x, d); if (lane >= d) x += t; }
  if (lane == 63) wsum[wid] = x;
  __syncthreads();
  int wexcl = 0;
  for (int q = 0; q < wid; ++q) wexcl += wsum[q];
  if (i < n) offs[i] = bex[blockIdx.x] + wexcl + x - v;
}

// ---------------- binned CSR fill: no atomics, windowed scatter ----------------
template <int EPT, int NPASS>
__global__ void k_fillb(const int* __restrict__ src, const int* __restrict__ dst,
                        const float* __restrict__ ew, const int* __restrict__ rank,
                        const int* __restrict__ offs, int2* __restrict__ esw, int E) {
  const int t0 = blockIdx.x * (256 * EPT) + threadIdx.x;
  int p[EPT];
  int2 v[EPT];
#pragma unroll
  for (int u = 0; u < EPT; ++u) {
    int i = t0 + u * 256;
    bool ok = (i < E);
    int d = ok ? dst[i] : 0;
    int r = ok ? rank[i] : 0;
    v[u].x = ok ? src[i] : 0;
    v[u].y = ok ? __builtin_bit_cast(int, ew[i]) : 0;
    p[u] = ok ? (offs[d] + r) : -1;
  }
  const int wsz = (E + NPASS - 1) / NPASS;
#pragma unroll
  for (int ps = 0; ps < NPASS; ++ps) {
    const int lo = ps * wsz, hi = lo + wsz;
#pragma unroll
    for (int u = 0; u < EPT; ++u) {
      if (p[u] >= lo && p[u] < hi) esw[p[u]] = v[u];
    }
  }
}

// ---------------- W split: W[K][N] fp32 -> Wt_hi/Wt_lo [N][K] bf16 ----------------
__global__ void k_wsplit(const float* __restrict__ W, short* __restrict__ hi,
                         short* __restrict__ lo, int K, int N) {
  int t = blockIdx.x * blockDim.x + threadIdx.x;
  if (t < K * N) {
    int k = t / N, n = t % N;
    float f = W[t];
    unsigned short h = f2bf(f);
    hi[(size_t)n * K + k] = (short)h;
    lo[(size_t)n * K + k] = (short)f2bf(f - bf2f(h));
  }
}

// ---------------- MFMA GEMM: C[M,N] = (A * ns[:,None]) @ W ----------------
template <int K, int N, int WR, int WC>
__launch_bounds__(256, 2)
__global__ void k_gemm_mfma(const float* __restrict__ A, const float* __restrict__ ns,
                            const short* __restrict__ Wth, const short* __restrict__ Wtl,
                            float* __restrict__ C, int M) {
  constexpr int MR = 128 / WR / 16;
  constexpr int NC = N / WC / 16;
  __shared__ short8 Ah[4 * 128], Al[4 * 128];
  __shared__ short8 Bh[4 * N], Bl[4 * N];
  const int t = threadIdx.x;
  const int block_row = blockIdx.x * 128;
  const int lane = t & 63, wid = t >> 6;
  const int wr = wid / WC, wc = wid % WC;
  const int rowbase = wr * (128 / WR), colbase = wc * (N / WC);
  const int c = lane >> 4, lr = lane & 15;
  f32x4 acc[MR][NC] = {};
  const int r = t & 127;
  const int grow = block_row + r;
  float nsv = 0.f;
  if (t < 128 && grow < M) nsv = ns[grow];

  for (int k0 = 0; k0 < K; k0 += 32) {
    if (t < 128) {
      f32x4 v[8];
      if (grow < M) {
        const f32x4* ap = (const f32x4*)(A + (size_t)grow * K + k0);
#pragma unroll
        for (int i = 0; i < 8; ++i) v[i] = ap[i] * nsv;
      } else {
#pragma unroll
        for (int i = 0; i < 8; ++i) v[i] = f32x4{0.f, 0.f, 0.f, 0.f};
      }
#pragma unroll
      for (int cc = 0; cc < 4; ++cc) {
        short8 hi, lo;
#pragma unroll
        for (int i = 0; i < 8; ++i) {
          float f = v[cc * 2 + (i >> 2)][i & 3];
          unsigned short h = f2bf(f);
          hi[i] = (short)h;
          lo[i] = (short)f2bf(f - bf2f(h));
        }
        Ah[cc * 128 + r] = hi;
        Al[cc * 128 + r] = lo;
      }
    } else {
      const int tt = t - 128;
#pragma unroll
      for (int id = tt; id < N * 4; id += 128) {
        int col = id & (N - 1);
        int cb = id / N;
        Bh[cb * N + col] = *(const short8*)(Wth + (size_t)col * K + k0 + cb * 8);
        Bl[cb * N + col] = *(const short8*)(Wtl + (size_t)col * K + k0 + cb * 8);
      }
    }
    __syncthreads();
    short8 ah[MR], al[MR], bh[NC], bl[NC];
#pragma unroll
    for (int m = 0; m < MR; ++m) {
      int row = rowbase + m * 16 + lr;
      ah[m] = Ah[c * 128 + row];
      al[m] = Al[c * 128 + row];
    }
#pragma unroll
    for (int n = 0; n < NC; ++n) {
      int col = colbase + n * 16 + lr;
      bh[n] = Bh[c * N + col];
      bl[n] = Bl[c * N + col];
    }
#pragma unroll
    for (int m = 0; m < MR; ++m)
#pragma unroll
      for (int n = 0; n < NC; ++n) {
        acc[m][n] = __builtin_amdgcn_mfma_f32_16x16x32_bf16(ah[m], bh[n], acc[m][n], 0, 0, 0);
        acc[m][n] = __builtin_amdgcn_mfma_f32_16x16x32_bf16(ah[m], bl[n], acc[m][n], 0, 0, 0);
        acc[m][n] = __builtin_amdgcn_mfma_f32_16x16x32_bf16(al[m], bh[n], acc[m][n], 0, 0, 0);
      }
    __syncthreads();
  }
#pragma unroll
  for (int m = 0; m < MR; ++m) {
#pragma unroll
    for (int j = 0; j < 4; ++j) {
      int row = block_row + rowbase + m * 16 + (lane >> 4) * 4 + j;
      if (row < M) {
#pragma unroll
        for (int n = 0; n < NC; ++n)
          C[(size_t)row * N + colbase + n * 16 + lr] = acc[m][n][j];
      }
    }
  }
}

// ---------------- aggregation D=128: wave/node, packed edges, unroll-8 gathers ----------------
__global__ void k_agg128(const float* __restrict__ h, const int* __restrict__ offs,
                         const int2* __restrict__ esw, const float* __restrict__ nd,
                         const float* __restrict__ bias, float* __restrict__ out, int M) {
  int w = blockIdx.x * (blockDim.x >> 6) + (threadIdx.x >> 6);
  int lane = threadIdx.x & 63;
  if (w >= M) return;
  int s0 = offs[w], s1 = offs[w + 1];
  const f32x2* hp = (const f32x2*)h;
  float a0 = 0.f, a1 = 0.f;
  for (int base = s0; base < s1; base += 64) {
    int kk = base + lane;
    int sidx = 0;
    float wt = 0.f;
    if (kk < s1) {
      int2 e = esw[kk];
      sidx = e.x;
      wt = __builtin_bit_cast(float, e.y);
    }
    int cnt = min(64, s1 - base);
    for (int jj = 0; jj < cnt; jj += 8) {
      f32x2 v[8];
      float wu[8];
#pragma unroll
      for (int u = 0; u < 8; ++u) {
        int s = rdlane_i(sidx, jj + u);
        wu[u] = rdlane_f(wt, jj + u);
        v[u] = hp[(size_t)(unsigned)s * 64 + lane];
      }
#pragma unroll
      for (int u = 0; u < 8; ++u) {
        a0 += v[u][0] * wu[u];
        a1 += v[u][1] * wu[u];
      }
    }
  }
  float ndv = nd[w];
  f32x2 b = ((const f32x2*)bias)[lane];
  f32x2 rr;
  rr[0] = fmaxf(a0 * ndv + b[0], 0.f);
  rr[1] = fmaxf(a1 * ndv + b[1], 0.f);
  ((f32x2*)out)[(size_t)w * 64 + lane] = rr;
}

// ---------------- aggregation D=64 fused with 64->1 matvec ----------------
__global__ void k_agg64mv(const float* __restrict__ h, const int* __restrict__ offs,
                          const int2* __restrict__ esw, const float* __restrict__ nd,
                          const float* __restrict__ b2, const float* __restrict__ W3,
                          const float* __restrict__ ns, float* __restrict__ h3, int M) {
  int w = blockIdx.x * (blockDim.x >> 6) + (threadIdx.x >> 6);
  int lane = threadIdx.x & 63;
  if (w >= M) return;
  int s0 = offs[w], s1 = offs[w + 1];
  float acc = 0.f;
  for (int base = s0; base < s1; base += 64) {
    int kk = base + lane;
    int sidx = 0;
    float wt = 0.f;
    if (kk < s1) {
      int2 e = esw[kk];
      sidx = e.x;
      wt = __builtin_bit_cast(float, e.y);
    }
    int cnt = min(64, s1 - base);
    for (int jj = 0; jj < cnt; jj += 8) {
      float v[8], wu[8];
#pragma unroll
      for (int u = 0; u < 8; ++u) {
        int s = rdlane_i(sidx, jj + u);
        wu[u] = rdlane_f(wt, jj + u);
        v[u] = h[(size_t)(unsigned)s * 64 + lane];
      }
#pragma unroll
      for (int u = 0; u < 8; ++u) acc += v[u] * wu[u];
    }
  }
  float r = fmaxf(acc * nd[w] + b2[lane], 0.f);
  float p = r * W3[lane];
#pragma unroll
  for (int d = 32; d; d >>= 1) p += __shfl_xor(p, d);
  if (lane == 0) h3[w] = p * ns[w];
}

// ---------------- final scalar aggregation ----------------
__global__ void k_aggfin(const float* __restrict__ h3, const int* __restrict__ offs,
                         const int2* __restrict__ esw, const float* __restrict__ nd,
                         const float* __restrict__ b3, float* __restrict__ out, int M) {
  int i = blockIdx.x * blockDim.x + threadIdx.x;
  if (i >= M) return;
  int s0 = offs[i], s1 = offs[i + 1];
  float acc = 0.f;
  int k = s0;
  for (; k + 4 <= s1; k += 4) {
    int2 e0 = esw[k], e1 = esw[k + 1], e2 = esw[k + 2], e3 = esw[k + 3];
    acc += h3[e0.x] * __builtin_bit_cast(float, e0.y)
         + h3[e1.x] * __builtin_bit_cast(float, e1.y)
         + h3[e2.x] * __builtin_bit_cast(float, e2.y)
         + h3[e3.x] * __builtin_bit_cast(float, e3.y);
  }
  for (; k < s1; ++k) {
    int2 e = esw[k];
    acc += h3[e.x] * __builtin_bit_cast(float, e.y);
  }
  out[i] = acc * nd[i] + b3[0];
}

extern "C" void kernel_launch(void* const* d_in, const int* in_sizes, int n_in,
                              void* d_out, int out_size, void* d_ws, size_t ws_size,
                              hipStream_t stream) {
  const float* b_z = (const float*)d_in[0];
  const int*   src = (const int*)d_in[1];
  const int*   dst = (const int*)d_in[2];
  const float* ew  = (const float*)d_in[3];
  const float* W1  = (const float*)d_in[5];
  const float* b1  = (const float*)d_in[6];
  const float* W2  = (const float*)d_in[7];
  const float* b2  = (const float*)d_in[8];
  const float* W3  = (const float*)d_in[9];
  const float* b3  = (const float*)d_in[10];
  const int N = in_sizes[0] / D0;
  const int E = in_sizes[1];
  float* out = (float*)d_out;

  char* ws = (char*)d_ws;
  size_t off_b = 0;
  auto alloc = [&](size_t bytes) -> void* {
    void* p = ws + off_b;
    off_b += (bytes + 255) & ~(size_t)255;
    return p;
  };
  int*   deg_out = (int*)alloc((size_t)N * 4);
  int*   deg_in  = (int*)alloc((size_t)N * 4);
  int*   offs    = (int*)alloc((size_t)(N + 1) * 4);
  int*   bsum    = (int*)alloc((size_t)1024 * 4);
  int2*  esw     = (int2*)alloc((size_t)E * 8);
  float* nsrc    = (float*)alloc((size_t)N * 4);
  float* ndst    = (float*)alloc((size_t)N * 4);
  float* h1      = (float*)alloc((size_t)N * D1 * 4);
  float* z1      = (float*)alloc((size_t)N * D1 * 4);
  float* h3      = (float*)alloc((size_t)N * 4);
  short* wt1h    = (short*)alloc((size_t)D0 * D1 * 2);
  short* wt1l    = (short*)alloc((size_t)D0 * D1 * 2);
  short* wt2h    = (short*)alloc((size_t)D1 * D2 * 2);
  short* wt2l    = (short*)alloc((size_t)D1 * D2 * 2);
  float* h2   = h1;        // layer-2 GEMM output reuses h1 (dead after agg128)
  int*   rank = (int*)z1;  // rank dead before z1 is first written (agg128)

  const int nb = (N + 255) / 256;

  hipMemsetAsync(deg_out, 0, (size_t)N * 4, stream);
  hipMemsetAsync(deg_in, 0, (size_t)N * 4, stream);
  k_degrees<<<(E + 255) / 256, 256, 0, stream>>>(src, dst, deg_out, deg_in, rank, E);
  k_norms<<<(N + 255) / 256, 256, 0, stream>>>(deg_out, deg_in, nsrc, ndst, N);
  k_bsum<<<nb, 256, 0, stream>>>(deg_in, bsum, N);
  k_bscan<<<1, 1024, 0, stream>>>(bsum, nb, &offs[N]);
  k_bscan2<<<nb, 256, 0, stream>>>(deg_in, bsum, offs, N);
  k_fillb<8, 8><<<(E + 2047) / 2048, 256, 0, stream>>>(src, dst, ew, rank, offs, esw, E);
  k_wsplit<<<(D0 * D1 + 255) / 256, 256, 0, stream>>>(W1, wt1h, wt1l, D0, D1);
  k_wsplit<<<(D1 * D2 + 255) / 256, 256, 0, stream>>>(W2, wt2h, wt2l, D1, D2);

  const int gemm_grid = (N + 127) / 128;
  // layer 1: 256 -> 128
  k_gemm_mfma<D0, D1, 2, 2><<<gemm_grid, 256, 0, stream>>>(b_z, nsrc, wt1h, wt1l, h1, N);
  k_agg128<<<(N + 3) / 4, 256, 0, stream>>>(h1, offs, esw, ndst, b1, z1, N);
  // layer 2: 128 -> 64
  k_gemm_mfma<D1, D2, 4, 1><<<gemm_grid, 256, 0, stream>>>(z1, nsrc, wt2h, wt2l, h2, N);
  // layer-2 agg fused with layer-3 projection (64->1 matvec)
  k_agg64mv<<<(N + 3) / 4, 256, 0, stream>>>(h2, offs, esw, ndst, b2, W3, nsrc, h3, N);
  // final scalar aggregation
  k_aggfin<<<(N + 255) / 256, 256, 0, stream>>>(h3, offs, esw, ndst, b3, out, N);
}